// Round 8
// baseline (632.844 us; speedup 1.0000x reference)
//
#include <hip/hip_runtime.h>
#include <stdint.h>
#include <stddef.h>

typedef unsigned short u16;
using f16    = _Float16;
using f16x2  = __attribute__((ext_vector_type(2))) _Float16;
using f16x8  = __attribute__((ext_vector_type(8))) _Float16;
using bf16x8 = __attribute__((ext_vector_type(8))) short;
using f32x4  = __attribute__((ext_vector_type(4))) float;

__device__ __forceinline__ short f2bf(float f) {
  uint32_t u = __builtin_bit_cast(uint32_t, f);
  u += 0x7FFFu + ((u >> 16) & 1u);   // RNE
  return (short)(u >> 16);
}
__device__ __forceinline__ u16 f2h(float f) {
  return __builtin_bit_cast(u16, (f16)f);
}

// async global->LDS, 16B per lane; LDS dest must be wave-contiguous (m97/m104)
typedef const __attribute__((address_space(1))) void* gas_t;
typedef __attribute__((address_space(3))) void* las_t;
__device__ __forceinline__ void async16(const void* g, void* l) {
  __builtin_amdgcn_global_load_lds((gas_t)g, (las_t)l, 16, 0, 0);
}

// sum of 8 f16 lanes into fp32 acc via 4x v_dot2_f32_f16
__device__ __forceinline__ float dot8(f16x8 v, float acc) {
  union { f16x8 v8; f16x2 v2[4]; } u;
  u.v8 = v;
  const f16x2 one2 = {(f16)1, (f16)1};
  acc = __builtin_amdgcn_fdot2(u.v2[0], one2, acc, false);
  acc = __builtin_amdgcn_fdot2(u.v2[1], one2, acc, false);
  acc = __builtin_amdgcn_fdot2(u.v2[2], one2, acc, false);
  acc = __builtin_amdgcn_fdot2(u.v2[3], one2, acc, false);
  return acc;
}
// horizontal max of f16x8 -> float
__device__ __forceinline__ float hmax8(f16x8 v) {
  union { f16x8 v8; f16x2 v2[4]; } u;
  u.v8 = v;
  f16x2 a = __builtin_elementwise_max(u.v2[0], u.v2[1]);
  f16x2 b = __builtin_elementwise_max(u.v2[2], u.v2[3]);
  f16x2 c = __builtin_elementwise_max(a, b);
  return fmaxf((float)c[0], (float)c[1]);
}

// ---- wave64 reductions via DPP (VALU pipe, no LDS) -------------------------
__device__ __forceinline__ float dpp_rsum(float x) {
  int v;
  v = __builtin_amdgcn_update_dpp(0, __builtin_bit_cast(int, x), 0xB1, 0xf, 0xf, false);
  x += __builtin_bit_cast(float, v);
  v = __builtin_amdgcn_update_dpp(0, __builtin_bit_cast(int, x), 0x4E, 0xf, 0xf, false);
  x += __builtin_bit_cast(float, v);
  v = __builtin_amdgcn_update_dpp(0, __builtin_bit_cast(int, x), 0x141, 0xf, 0xf, false);
  x += __builtin_bit_cast(float, v);
  v = __builtin_amdgcn_update_dpp(0, __builtin_bit_cast(int, x), 0x140, 0xf, 0xf, false);
  x += __builtin_bit_cast(float, v);
  v = __builtin_amdgcn_update_dpp(0, __builtin_bit_cast(int, x), 0x142, 0xa, 0xf, false);
  x += __builtin_bit_cast(float, v);
  v = __builtin_amdgcn_update_dpp(0, __builtin_bit_cast(int, x), 0x143, 0xc, 0xf, false);
  x += __builtin_bit_cast(float, v);
  return __builtin_bit_cast(float, __builtin_amdgcn_readlane(__builtin_bit_cast(int, x), 63));
}
__device__ __forceinline__ float dpp_rmax(float x) {
  const int NINF = 0xFF800000;
  int v;
  v = __builtin_amdgcn_update_dpp(NINF, __builtin_bit_cast(int, x), 0xB1, 0xf, 0xf, false);
  x = fmaxf(x, __builtin_bit_cast(float, v));
  v = __builtin_amdgcn_update_dpp(NINF, __builtin_bit_cast(int, x), 0x4E, 0xf, 0xf, false);
  x = fmaxf(x, __builtin_bit_cast(float, v));
  v = __builtin_amdgcn_update_dpp(NINF, __builtin_bit_cast(int, x), 0x141, 0xf, 0xf, false);
  x = fmaxf(x, __builtin_bit_cast(float, v));
  v = __builtin_amdgcn_update_dpp(NINF, __builtin_bit_cast(int, x), 0x140, 0xf, 0xf, false);
  x = fmaxf(x, __builtin_bit_cast(float, v));
  v = __builtin_amdgcn_update_dpp(NINF, __builtin_bit_cast(int, x), 0x142, 0xa, 0xf, false);
  x = fmaxf(x, __builtin_bit_cast(float, v));
  v = __builtin_amdgcn_update_dpp(NINF, __builtin_bit_cast(int, x), 0x143, 0xc, 0xf, false);
  x = fmaxf(x, __builtin_bit_cast(float, v));
  return __builtin_bit_cast(float, __builtin_amdgcn_readlane(__builtin_bit_cast(int, x), 63));
}

// ---- full-row sparsemax solver (fallback + standalone path) ----------------
// Pure Newton from max((s-1)/M, m-1); monotone from below, cap 6 passes.
__device__ __forceinline__ float solve_tau(const f16x8* z) {
  const f16 bg = (f16)65504.0f;
  const f16x8 big8  = {bg, bg, bg, bg, bg, bg, bg, bg};
  const f16x8 one8  = {(f16)1, (f16)1, (f16)1, (f16)1, (f16)1, (f16)1, (f16)1, (f16)1};
  const f16x8 zero8 = {(f16)0, (f16)0, (f16)0, (f16)0, (f16)0, (f16)0, (f16)0, (f16)0};

  float sA = 0.f, sB = 0.f;
  f16x8 mx = z[0];
#pragma unroll
  for (int t = 0; t < 8; t += 2) {
    sA = dot8(z[t], sA);
    sB = dot8(z[t + 1], sB);
  }
#pragma unroll
  for (int t = 1; t < 8; ++t) mx = __builtin_elementwise_max(mx, z[t]);

  float s = dpp_rsum(sA + sB);
  float m = dpp_rmax(hmax8(mx));

  float tau = fmaxf((s - 1.0f) * (1.0f / 4096.0f), m - 1.0f);

#pragma unroll 1
  for (int it = 0; it < 6; ++it) {
    f16 tq = (f16)tau;
    f16x8 t8 = {tq, tq, tq, tq, tq, tq, tq, tq};
    float lsA = 0.f, lsB = 0.f, lcA = 0.f, lcB = 0.f;
#pragma unroll
    for (int t = 0; t < 8; t += 2) {
      f16x8 ma = __builtin_elementwise_max(z[t] - t8, zero8);
      f16x8 mb = __builtin_elementwise_max(z[t + 1] - t8, zero8);
      lsA = dot8(ma, lsA);
      lsB = dot8(mb, lsB);
      lcA = dot8(__builtin_elementwise_min(ma * big8, one8), lcA);
      lcB = dot8(__builtin_elementwise_min(mb * big8, one8), lcB);
    }
    float ls = dpp_rsum(lsA + lsB);
    float lc = dpp_rsum(lcA + lcB);
    if (lc < 0.5f) break;
    float nt = tau + (ls - 1.0f) / lc;
    if (nt == tau) break;
    tau = nt;
  }
  return tau;
}

// ---------------------------------------------------------------- convert ---
struct ConvArgs {
  const float* src[8];
  u16* dst[8];
  int start4[9];   // exclusive prefix in float4 units
};

__global__ __launch_bounds__(256) void convert_all(ConvArgs a) {
  int idx = blockIdx.x * 256 + threadIdx.x;
  if (idx >= a.start4[8]) return;
  int s = 0;
#pragma unroll
  for (int i = 1; i < 8; ++i) s += (idx >= a.start4[i]) ? 1 : 0;
  int off = idx - a.start4[s];
  const float4* sp = (const float4*)a.src[s];
  float4 v = sp[off];
  ushort4 o;
  o.x = (u16)f2bf(v.x); o.y = (u16)f2bf(v.y);
  o.z = (u16)f2bf(v.z); o.w = (u16)f2bf(v.w);
  *(ushort4*)(a.dst[s] + (size_t)off * 4) = o;
}

__global__ __launch_bounds__(256) void zero_u16(u16* p, int n) {
  int i = blockIdx.x * 256 + threadIdx.x;
  if (i < n) p[i] = 0;
}

// ------------------------------------------------------------------- GEMM ---
// C[M,N] = A[M,K1] @ B[N,K1]^T (+ A2@B2^T if DUAL) + bias, then *escale,
// optional relu. m97 structure, global_load_lds width-16 staging.
// NOTE (R4/R5): these small-K GEMMs need >= 2 co-resident blocks/CU
// (>= 512 blocks on 256 CUs); TM=128 grids of 256 blocks regressed.
template<int BIAS, bool RELU, int OUTT, bool DUAL, int TM, int IN>
__global__ __launch_bounds__(256) void gemm_nt(
    const u16* __restrict__ A, int lda,
    const u16* __restrict__ B, int ldb,
    const u16* __restrict__ A2, int lda2,
    const u16* __restrict__ B2, int ldb2,
    int K1, int K2,
    const float* __restrict__ bias,
    void* __restrict__ C, int ldc, int N,
    float escale, size_t bzA, size_t bzB, size_t bzC)
{
  constexpr int MI = (TM == 128) ? 4 : 2;   // 16-row m-frags per wave
  __shared__ u16 As[TM * 32];
  __shared__ u16 Bs[128 * 32];

  const size_t zo = (size_t)blockIdx.z;
  A += zo * bzA;
  B += zo * bzB;
  u16*   C16 = (u16*)C + zo * bzC;
  float* C32 = (float*)C + zo * bzC;

  const int tid  = threadIdx.x;
  const int m0   = blockIdx.y * TM;
  const int n0   = blockIdx.x * 128;
  const int wave = tid >> 6, lane = tid & 63;
  const int lrow = lane & 15, quad = lane >> 4;
  const int wm   = (TM == 128) ? (wave & 1) * 64 : (wave >> 1) * 32;
  const int wn   = (TM == 128) ? (wave >> 1) * 64 : (wave & 1) * 64;

  f32x4 zero = {0.f, 0.f, 0.f, 0.f};
  f32x4 acc[MI][4];
#pragma unroll
  for (int i = 0; i < MI; ++i)
#pragma unroll
    for (int j = 0; j < 4; ++j) acc[i][j] = zero;

  const int KK = DUAL ? (K1 + K2) : K1;
  for (int k0 = 0; k0 < KK; k0 += 32) {
    const u16* Ap; const u16* Bp; int la, lb, kk;
    if (!DUAL || k0 < K1) { Ap = A;  Bp = B;  la = lda;  lb = ldb;  kk = k0; }
    else                  { Ap = A2; Bp = B2; la = lda2; lb = ldb2; kk = k0 - K1; }

#pragma unroll
    for (int i = 0; i < TM / 64; ++i) {       // A: TM*4 chunks of 16B
      int idx = i * 256 + tid;
      int row = idx >> 2, c8 = (idx & 3) * 8;
      async16(Ap + (size_t)(m0 + row) * la + kk + c8, &As[idx * 8]);
    }
#pragma unroll
    for (int i = 0; i < 2; ++i) {             // B: 512 chunks of 16B
      int idx = i * 256 + tid;
      int row = idx >> 2, c8 = (idx & 3) * 8;
      async16(Bp + (size_t)(n0 + row) * lb + kk + c8, &Bs[idx * 8]);
    }
    __syncthreads();

    bf16x8 af[MI], bfr[4];
#pragma unroll
    for (int i = 0; i < MI; ++i)
      af[i] = *(const bf16x8*)(&As[(wm + i * 16 + lrow) * 32 + quad * 8]);
#pragma unroll
    for (int j = 0; j < 4; ++j)
      bfr[j] = *(const bf16x8*)(&Bs[(wn + j * 16 + lrow) * 32 + quad * 8]);
#pragma unroll
    for (int i = 0; i < MI; ++i)
#pragma unroll
      for (int j = 0; j < 4; ++j) {
        if constexpr (IN == 0)
          acc[i][j] = __builtin_amdgcn_mfma_f32_16x16x32_bf16(af[i], bfr[j], acc[i][j], 0, 0, 0);
        else
          acc[i][j] = __builtin_amdgcn_mfma_f32_16x16x32_f16(
              __builtin_bit_cast(f16x8, af[i]), __builtin_bit_cast(f16x8, bfr[j]),
              acc[i][j], 0, 0, 0);
      }
    __syncthreads();
  }

  // epilogue: C layout col=lane&15, row=quad*4+r
#pragma unroll
  for (int i = 0; i < MI; ++i) {
#pragma unroll
    for (int j = 0; j < 4; ++j) {
      int gn = n0 + wn + j * 16 + lrow;
      if (gn >= N) continue;
      float bc = (BIAS == 1) ? bias[gn] : 0.0f;
#pragma unroll
      for (int r = 0; r < 4; ++r) {
        int gm = m0 + wm + i * 16 + quad * 4 + r;
        float v = acc[i][j][r] + bc;
        if (BIAS == 2) v += bias[gm];
        v *= escale;
        if (RELU) v = fmaxf(v, 0.0f);
        if (OUTT == 1)      C16[(size_t)gm * ldc + gn] = (u16)f2bf(v);
        else if (OUTT == 2) C16[(size_t)gm * ldc + gn] = f2h(v);
        else                C32[(size_t)gm * ldc + gn] = v;
      }
    }
  }
}

// ------------------------------------------------- standalone sparsemax -----
__global__ __launch_bounds__(256) void sparsemax_rows(u16* __restrict__ Sp) {
  const int wave = threadIdx.x >> 6, lane = threadIdx.x & 63;
  const int wid  = blockIdx.x * 4 + wave;
  const f16x8 zero8 = {(f16)0, (f16)0, (f16)0, (f16)0, (f16)0, (f16)0, (f16)0, (f16)0};

#pragma unroll 1
  for (int rr = 0; rr < 2; ++rr) {
    const size_t row = (size_t)wid * 2 + rr;
    f16* Srow = (f16*)Sp + row * 4096;
    f16x8 z[8];
#pragma unroll
    for (int t = 0; t < 8; ++t)
      z[t] = *(const f16x8*)(Srow + t * 512 + lane * 8);

    float tau = solve_tau(z);

    f16 tq = (f16)tau;
    f16x8 t8 = {tq, tq, tq, tq, tq, tq, tq, tq};
#pragma unroll
    for (int t = 0; t < 8; ++t)
      *(f16x8*)(Srow + t * 512 + lane * 8) =
          __builtin_elementwise_max(z[t] - t8, zero8);
  }
}

// ------------------------------------------------- fused attention v6 -------
// Key-half staging (65.8 KB LDS -> 2 blocks/CU = 32 waves, wave cap).
// v6: deepened MLP. The kernel is K/V L2-LATENCY bound (Little's law:
// ~40 GB/s/CU demanded, 2-4 loads in flight deliver ~15-25). QK^T runs a
// 3-deep rotating K prefetch (6 loads in flight); PV issues BOTH first V
// pairs before the P-write barrier and rotates 2 pairs deep (4-8 in flight).
// All rotation indices compile-time (full unroll, rule #20). Peak live
// VGPR ~56 of the 64 cap.
__global__ __launch_bounds__(1024, 8) void attn_sparsemax2(
    const f16* __restrict__ Q,    // [2048][1024] f16 (pre-scaled)
    const f16* __restrict__ Km,   // [4096][1024] f16
    const f16* __restrict__ Vt,   // [1024][4096] f16 (V transposed)
    u16* __restrict__ AO)         // [2048][1024] bf16
{
  constexpr int HROW = 2048 + 8;                 // f16 per row, half-keys + pad
  __shared__ __align__(16) char ldsbuf[16 * HROW * 2];   // 65,792 B
  f16*   S    = (f16*)ldsbuf;
  float* Ored = (float*)ldsbuf;                  // [kseg][dhg][256], aliased

  const int id    = blockIdx.x;
  const int head  = (id & 7) * 2 + ((id >> 3) >> 7);
  const int qblk  = (id >> 3) & 127;
  const int qbase = qblk * 16;
  const int tid   = threadIdx.x;
  const int wave  = tid >> 6, lane = tid & 63;
  const int lrow  = lane & 15, quad = lane >> 4;

  const f16* qp = Q + (size_t)(qbase + lrow) * 1024 + head * 64 + quad * 8;
  f16x8 qf0 = *(const f16x8*)qp;
  f16x8 qf1 = *(const f16x8*)(qp + 32);

  f16x8 z[8];

  // ---- QK^T in two key-halves; 3-deep rotating K prefetch ----
#pragma unroll
  for (int H = 0; H < 2; ++H) {
    const f16* kpb = Km + (size_t)(H * 2048 + wave * 128 + lrow) * 1024
                        + head * 64 + quad * 8;
    f16x8 kfa[3], kfb[3];
#pragma unroll
    for (int i = 0; i < 3; ++i) {
      kfa[i] = *(const f16x8*)(kpb + (size_t)i * 16 * 1024);
      kfb[i] = *(const f16x8*)(kpb + (size_t)i * 16 * 1024 + 32);
    }
#pragma unroll
    for (int kt = 0; kt < 8; ++kt) {
      f16x8 kf0 = kfa[kt % 3], kf1 = kfb[kt % 3];
      if (kt < 5) {                              // refill the consumed slot
        kfa[kt % 3] = *(const f16x8*)(kpb + (size_t)(kt + 3) * 16 * 1024);
        kfb[kt % 3] = *(const f16x8*)(kpb + (size_t)(kt + 3) * 16 * 1024 + 32);
      }
      f32x4 sc = {0.f, 0.f, 0.f, 0.f};
      __builtin_amdgcn_s_setprio(1);
      sc = __builtin_amdgcn_mfma_f32_16x16x32_f16(qf0, kf0, sc, 0, 0, 0);
      sc = __builtin_amdgcn_mfma_f32_16x16x32_f16(qf1, kf1, sc, 0, 0, 0);
      __builtin_amdgcn_s_setprio(0);
      int lk = wave * 128 + kt * 16;             // local (in-half) key col
#pragma unroll
      for (int r = 0; r < 4; ++r)
        S[(quad * 4 + r) * HROW + lk + lrow] = (f16)sc[r];
    }
    __syncthreads();
#pragma unroll
    for (int t = 0; t < 4; ++t)
      z[H * 4 + t] = *(const f16x8*)(&S[wave * HROW + t * 512 + lane * 8]);
    __syncthreads();   // all reads done before tile is overwritten
  }

  // ---- candidate-compact sparsemax solve ----
  float m;
  {
    f16x8 mx = z[0];
#pragma unroll
    for (int t = 1; t < 8; ++t) mx = __builtin_elementwise_max(mx, z[t]);
    m = dpp_rmax(hmax8(mx));
  }
  float tau;
  f16* cbuf = &S[wave * HROW];            // own strip: exclusive until P-write
  f16  thr_h = (f16)(m - 1.01f);          // margin so RNE stays <= m-1
  bool compact_ok = ((float)thr_h <= m - 1.0f);
  int cnt = 0;
  if (compact_ok) {
#pragma unroll
    for (int t = 0; t < 8; ++t) {
#pragma unroll
      for (int j = 0; j < 8; ++j) {
        bool c = (z[t][j] > thr_h);
        unsigned long long mk = __ballot(c);
        if (mk) {                          // wave-uniform skip (most elems)
          if (c) {
            int slot = cnt + __builtin_amdgcn_mbcnt_hi(
                (unsigned)(mk >> 32),
                __builtin_amdgcn_mbcnt_lo((unsigned)mk, 0));
            if (slot < 64) cbuf[slot] = z[t][j];
          }
          cnt += (int)__popcll(mk);
        }
      }
    }
  }
  if (compact_ok && cnt <= 64) {
    asm volatile("s_waitcnt lgkmcnt(0)" ::: "memory");
    f16 craw = cbuf[lane];
    const f16 nbig = (f16)-65504.0f;
    f16 cand = (lane < cnt) ? craw : nbig;
    tau = m - 1.0f;
#pragma unroll 1
    for (int it = 0; it < 8; ++it) {
      // f16 elementwise math matches the full-row path exactly
      f16 tq = (f16)tau;
      f16 dh = cand - tq;
      f16 rh = (dh > (f16)0) ? dh : (f16)0;
      f16 ih = rh * (f16)65504.0f;
      ih = (ih < (f16)1) ? ih : (f16)1;
      float ls = dpp_rsum((float)rh);
      float lc = dpp_rsum((float)ih);
      if (lc < 0.5f) break;
      float nt = tau + (ls - 1.0f) / lc;
      if (nt == tau) break;
      tau = nt;
    }
  } else {
    tau = solve_tau(z);                    // full-row fallback (rare)
  }

  const f16 tq = (f16)tau;
  const f16x8 t8 = {tq, tq, tq, tq, tq, tq, tq, tq};
  const f16x8 zero8 = {(f16)0, (f16)0, (f16)0, (f16)0, (f16)0, (f16)0, (f16)0, (f16)0};

  const int dhg = wave & 3, kseg = wave >> 2;    // 4 dh-groups x 4 k-segments
  f32x4 oacc0 = {0.f, 0.f, 0.f, 0.f};
  f32x4 oacc1 = {0.f, 0.f, 0.f, 0.f};
  const f16* vbase = Vt + (size_t)(head * 64 + dhg * 16 + lrow) * 4096
                        + kseg * 512 + quad * 8;
  const f16* prow  = &S[lrow * HROW + kseg * 512 + quad * 8];

  // ---- P write + PV, per key-half; 2-pair-deep V prefetch ----
#pragma unroll
  for (int H = 0; H < 2; ++H) {
    const f16* vrow = vbase + H * 2048;
    // issue BOTH first V pairs before the barrier: latency hides under the
    // P-write + barrier rendezvous (V depends on nothing in LDS)
    f16x8 vfa[2], vfb[2];
    vfa[0] = *(const f16x8*)(vrow);
    vfb[0] = *(const f16x8*)(vrow + 32);
    vfa[1] = *(const f16x8*)(vrow + 64);
    vfb[1] = *(const f16x8*)(vrow + 96);
#pragma unroll
    for (int t = 0; t < 4; ++t)
      *(f16x8*)(&S[wave * HROW + t * 512 + lane * 8]) =
          __builtin_elementwise_max(z[H * 4 + t] - t8, zero8);
    __syncthreads();
#pragma unroll
    for (int p = 0; p < 8; ++p) {          // pair index: keys [p*32, p*32+64)
      f16x8 vf0 = vfa[p & 1], vf1 = vfb[p & 1];
      if (p < 6) {                          // refill consumed slot, 2 ahead
        vfa[p & 1] = *(const f16x8*)(vrow + (p + 2) * 64);
        vfb[p & 1] = *(const f16x8*)(vrow + (p + 2) * 64 + 32);
      }
      f16x8 pf0 = *(const f16x8*)(prow + p * 64);
      f16x8 pf1 = *(const f16x8*)(prow + p * 64 + 32);
      __builtin_amdgcn_s_setprio(1);
      oacc0 = __builtin_amdgcn_mfma_f32_16x16x32_f16(pf0, vf0, oacc0, 0, 0, 0);
      oacc1 = __builtin_amdgcn_mfma_f32_16x16x32_f16(pf1, vf1, oacc1, 0, 0, 0);
      __builtin_amdgcn_s_setprio(0);
    }
    __syncthreads();   // all P reads done (H=1: before Ored aliases S)
  }
  f32x4 oacc = oacc0 + oacc1;

  // ---- cross-kseg reduction via aliased Ored, then AO store ----
  float* orp = &Ored[(kseg * 4 + dhg) * 256];
#pragma unroll
  for (int r = 0; r < 4; ++r) orp[(quad * 4 + r) * 16 + lrow] = oacc[r];
  __syncthreads();
  if (kseg == 0) {
#pragma unroll
    for (int r = 0; r < 4; ++r) {
      int idx = (quad * 4 + r) * 16 + lrow;
      float v = oacc[r] + Ored[(1 * 4 + dhg) * 256 + idx]
                        + Ored[(2 * 4 + dhg) * 256 + idx]
                        + Ored[(3 * 4 + dhg) * 256 + idx];
      AO[(size_t)(qbase + quad * 4 + r) * 1024 + head * 64 + dhg * 16 + lrow] = (u16)f2bf(v);
    }
  }
}

// ---------------------------------------------------------------- launcher --
extern "C" void kernel_launch(void* const* d_in, const int* in_sizes, int n_in,
                              void* d_out, int out_size, void* d_ws, size_t ws_size,
                              hipStream_t stream) {
  const float* enc = (const float*)d_in[0];
  const float* mem = (const float*)d_in[1];
  const float* Wq  = (const float*)d_in[2];
  const float* bq  = (const float*)d_in[3];
  const float* Wk  = (const float*)d_in[4];
  const float* bk  = (const float*)d_in[5];
  const float* Wv  = (const float*)d_in[6];
  const float* bv  = (const float*)d_in[7];
  const float* Wo  = (const float*)d_in[8];
  const float* bo  = (const float*)d_in[9];
  const float* W1  = (const float*)d_in[10];
  const float* b1  = (const float*)d_in[11];
  const float* W2  = (const float*)d_in[12];
  const float* b2  = (const float*)d_in[13];

  char* ws = (char*)d_ws;
  const size_t MB = 1024 * 1024;
  u16* enc_bf = (u16*)(ws + 0 * MB);   // 2048x1024 bf16
  u16* mem_bf = (u16*)(ws + 4 * MB);   // 4096x1024 bf16
  u16* Wq_bf  = (u16*)(ws + 12 * MB);
  u16* Wk_bf  = (u16*)(ws + 14 * MB);
  u16* Wv_bf  = (u16*)(ws + 16 * MB);
  u16* Wo_bf  = (u16*)(ws + 18 * MB);
  u16* W1_bf  = (u16*)(ws + 20 * MB);  // 4096x2048
  u16* W2_bf  = (u16*)(ws + 36 * MB);  // 1024x4096 (padded from 1000)
  u16* Qb     = (u16*)(ws + 46 * MB);  // 2048x1024 f16 (pre-scaled by 1/32)
  u16* Kb     = (u16*)(ws + 50 * MB);  // 4096x1024 f16
  u16* Vtb    = (u16*)(ws + 58 * MB);  // 1024x4096 f16 (V^T)
  u16* AO     = (u16*)(ws + 66 * MB);  // 2048x1024 bf16
  u16* OUT    = (u16*)(ws + 70 * MB);  // 2048x1024 bf16
  u16* Hh     = (u16*)(ws + 74 * MB);  // 2048x4096 bf16
  u16* Sbuf   = (u16*)(ws + 96 * MB);  // 16x2048x4096 f16 = 256 MB (split path)

  const bool split = ws_size >= (size_t)360 * MB;  // constant per harness

  ConvArgs ca;
  const float* srcs[8] = {enc, mem, Wq, Wk, Wv, Wo, W1, W2};
  u16* dsts[8] = {enc_bf, mem_bf, Wq_bf, Wk_bf, Wv_bf, Wo_bf, W1_bf, W2_bf};
  int sizes[8] = {2048 * 1024, 4096 * 1024, 1024 * 1024, 1024 * 1024,
                  1024 * 1024, 1024 * 1024, 4096 * 2048, 1000 * 4096};
  int start = 0;
  for (int i = 0; i < 8; ++i) {
    ca.src[i] = srcs[i]; ca.dst[i] = dsts[i];
    ca.start4[i] = start; start += sizes[i] / 4;
  }
  ca.start4[8] = start;
  convert_all<<<(start + 255) / 256, 256, 0, stream>>>(ca);
  zero_u16<<<(24 * 4096 + 255) / 256, 256, 0, stream>>>(W2_bf + 1000 * 4096, 24 * 4096);

  // Q = (enc @ Wq^T + bq) / 32   (f16 out, scale folded)  [TM=64: 256 blocks]
  gemm_nt<1, false, 2, false, 64, 0><<<dim3(8, 32), 256, 0, stream>>>(
      enc_bf, 1024, Wq_bf, 1024, nullptr, 0, nullptr, 0, 1024, 0, bq,
      Qb, 1024, 1024, 1.0f / 32.0f, 0, 0, 0);
  // K = mem @ Wk^T + bk  (f16 out)  [TM=64: 512 blocks]
  gemm_nt<1, false, 2, false, 64, 0><<<dim3(8, 64), 256, 0, stream>>>(
      mem_bf, 1024, Wk_bf, 1024, nullptr, 0, nullptr, 0, 1024, 0, bk,
      Kb, 1024, 1024, 1.0f, 0, 0, 0);
  // V^T = Wv @ mem^T + bv (row bias, f16 out)  [TM=64: 512 blocks]
  gemm_nt<2, false, 2, false, 64, 0><<<dim3(32, 16), 256, 0, stream>>>(
      Wv_bf, 1024, mem_bf, 1024, nullptr, 0, nullptr, 0, 1024, 0, bv,
      Vtb, 4096, 4096, 1.0f, 0, 0, 0);

  if (split) {
    gemm_nt<0, false, 2, false, 128, 1><<<dim3(32, 16, 16), 256, 0, stream>>>(
        Qb, 1024, Kb, 1024, nullptr, 0, nullptr, 0, 64, 0, nullptr,
        Sbuf, 4096, 4096, 1.0f, 64, 64, (size_t)2048 * 4096);
    sparsemax_rows<<<4096, 256, 0, stream>>>(Sbuf);
    gemm_nt<0, false, 1, false, 64, 1><<<dim3(1, 32, 16), 256, 0, stream>>>(
        Sbuf, 4096, Vtb, 4096, nullptr, 0, nullptr, 0, 4096, 0, nullptr,
        AO, 1024, 64, 1.0f, (size_t)2048 * 4096, (size_t)64 * 4096, 64);
  } else {
    attn_sparsemax2<<<2048, 1024, 0, stream>>>(
        (const f16*)Qb, (const f16*)Kb, (const f16*)Vtb, AO);
  }

  // OUT = AO @ Wo^T + bo (bf16 out)  [TM=64: 256 blocks]
  gemm_nt<1, false, 1, false, 64, 0><<<dim3(8, 32), 256, 0, stream>>>(
      AO, 1024, Wo_bf, 1024, nullptr, 0, nullptr, 0, 1024, 0, bo,
      OUT, 1024, 1024, 1.0f, 0, 0, 0);
  // H = relu(enc@W1a^T + OUT@W1b^T + b1)  [TM=128: 512 blocks]
  gemm_nt<1, true, 1, true, 128, 0><<<dim3(32, 16), 256, 0, stream>>>(
      enc_bf, 1024, W1_bf, 2048, OUT, 1024, W1_bf + 1024, 2048, 1024, 1024, b1,
      Hh, 4096, 4096, 1.0f, 0, 0, 0);
  // out = H @ W2^T + b2 (fp32 out, N=1000)  [TM=64: 256 blocks]
  gemm_nt<1, false, 0, false, 64, 0><<<dim3(8, 32), 256, 0, stream>>>(
      Hh, 4096, W2_bf, 4096, nullptr, 0, nullptr, 0, 4096, 0, b2,
      d_out, 1000, 1000, 1.0f, 0, 0, 0);
}

// Round 9
// 600.753 us; speedup vs baseline: 1.0534x; 1.0534x over previous
//
#include <hip/hip_runtime.h>
#include <stdint.h>
#include <stddef.h>

typedef unsigned short u16;
using f16    = _Float16;
using f16x2  = __attribute__((ext_vector_type(2))) _Float16;
using f16x8  = __attribute__((ext_vector_type(8))) _Float16;
using bf16x8 = __attribute__((ext_vector_type(8))) short;
using f32x4  = __attribute__((ext_vector_type(4))) float;

__device__ __forceinline__ short f2bf(float f) {
  uint32_t u = __builtin_bit_cast(uint32_t, f);
  u += 0x7FFFu + ((u >> 16) & 1u);   // RNE
  return (short)(u >> 16);
}
__device__ __forceinline__ u16 f2h(float f) {
  return __builtin_bit_cast(u16, (f16)f);
}

// async global->LDS, 16B per lane; LDS dest must be wave-contiguous (m97/m104)
typedef const __attribute__((address_space(1))) void* gas_t;
typedef __attribute__((address_space(3))) void* las_t;
__device__ __forceinline__ void async16(const void* g, void* l) {
  __builtin_amdgcn_global_load_lds((gas_t)g, (las_t)l, 16, 0, 0);
}

// sum of 8 f16 lanes into fp32 acc via 4x v_dot2_f32_f16
__device__ __forceinline__ float dot8(f16x8 v, float acc) {
  union { f16x8 v8; f16x2 v2[4]; } u;
  u.v8 = v;
  const f16x2 one2 = {(f16)1, (f16)1};
  acc = __builtin_amdgcn_fdot2(u.v2[0], one2, acc, false);
  acc = __builtin_amdgcn_fdot2(u.v2[1], one2, acc, false);
  acc = __builtin_amdgcn_fdot2(u.v2[2], one2, acc, false);
  acc = __builtin_amdgcn_fdot2(u.v2[3], one2, acc, false);
  return acc;
}
// horizontal max of f16x8 -> float
__device__ __forceinline__ float hmax8(f16x8 v) {
  union { f16x8 v8; f16x2 v2[4]; } u;
  u.v8 = v;
  f16x2 a = __builtin_elementwise_max(u.v2[0], u.v2[1]);
  f16x2 b = __builtin_elementwise_max(u.v2[2], u.v2[3]);
  f16x2 c = __builtin_elementwise_max(a, b);
  return fmaxf((float)c[0], (float)c[1]);
}

// ---- wave64 reductions via DPP (VALU pipe, no LDS) -------------------------
__device__ __forceinline__ float dpp_rsum(float x) {
  int v;
  v = __builtin_amdgcn_update_dpp(0, __builtin_bit_cast(int, x), 0xB1, 0xf, 0xf, false);
  x += __builtin_bit_cast(float, v);
  v = __builtin_amdgcn_update_dpp(0, __builtin_bit_cast(int, x), 0x4E, 0xf, 0xf, false);
  x += __builtin_bit_cast(float, v);
  v = __builtin_amdgcn_update_dpp(0, __builtin_bit_cast(int, x), 0x141, 0xf, 0xf, false);
  x += __builtin_bit_cast(float, v);
  v = __builtin_amdgcn_update_dpp(0, __builtin_bit_cast(int, x), 0x140, 0xf, 0xf, false);
  x += __builtin_bit_cast(float, v);
  v = __builtin_amdgcn_update_dpp(0, __builtin_bit_cast(int, x), 0x142, 0xa, 0xf, false);
  x += __builtin_bit_cast(float, v);
  v = __builtin_amdgcn_update_dpp(0, __builtin_bit_cast(int, x), 0x143, 0xc, 0xf, false);
  x += __builtin_bit_cast(float, v);
  return __builtin_bit_cast(float, __builtin_amdgcn_readlane(__builtin_bit_cast(int, x), 63));
}
__device__ __forceinline__ float dpp_rmax(float x) {
  const int NINF = 0xFF800000;
  int v;
  v = __builtin_amdgcn_update_dpp(NINF, __builtin_bit_cast(int, x), 0xB1, 0xf, 0xf, false);
  x = fmaxf(x, __builtin_bit_cast(float, v));
  v = __builtin_amdgcn_update_dpp(NINF, __builtin_bit_cast(int, x), 0x4E, 0xf, 0xf, false);
  x = fmaxf(x, __builtin_bit_cast(float, v));
  v = __builtin_amdgcn_update_dpp(NINF, __builtin_bit_cast(int, x), 0x141, 0xf, 0xf, false);
  x = fmaxf(x, __builtin_bit_cast(float, v));
  v = __builtin_amdgcn_update_dpp(NINF, __builtin_bit_cast(int, x), 0x140, 0xf, 0xf, false);
  x = fmaxf(x, __builtin_bit_cast(float, v));
  v = __builtin_amdgcn_update_dpp(NINF, __builtin_bit_cast(int, x), 0x142, 0xa, 0xf, false);
  x = fmaxf(x, __builtin_bit_cast(float, v));
  v = __builtin_amdgcn_update_dpp(NINF, __builtin_bit_cast(int, x), 0x143, 0xc, 0xf, false);
  x = fmaxf(x, __builtin_bit_cast(float, v));
  return __builtin_bit_cast(float, __builtin_amdgcn_readlane(__builtin_bit_cast(int, x), 63));
}

// ---- full-row sparsemax solver (fallback + standalone path) ----------------
__device__ __forceinline__ float solve_tau(const f16x8* z) {
  const f16 bg = (f16)65504.0f;
  const f16x8 big8  = {bg, bg, bg, bg, bg, bg, bg, bg};
  const f16x8 one8  = {(f16)1, (f16)1, (f16)1, (f16)1, (f16)1, (f16)1, (f16)1, (f16)1};
  const f16x8 zero8 = {(f16)0, (f16)0, (f16)0, (f16)0, (f16)0, (f16)0, (f16)0, (f16)0};

  float sA = 0.f, sB = 0.f;
  f16x8 mx = z[0];
#pragma unroll
  for (int t = 0; t < 8; t += 2) {
    sA = dot8(z[t], sA);
    sB = dot8(z[t + 1], sB);
  }
#pragma unroll
  for (int t = 1; t < 8; ++t) mx = __builtin_elementwise_max(mx, z[t]);

  float s = dpp_rsum(sA + sB);
  float m = dpp_rmax(hmax8(mx));

  float tau = fmaxf((s - 1.0f) * (1.0f / 4096.0f), m - 1.0f);

#pragma unroll 1
  for (int it = 0; it < 6; ++it) {
    f16 tq = (f16)tau;
    f16x8 t8 = {tq, tq, tq, tq, tq, tq, tq, tq};
    float lsA = 0.f, lsB = 0.f, lcA = 0.f, lcB = 0.f;
#pragma unroll
    for (int t = 0; t < 8; t += 2) {
      f16x8 ma = __builtin_elementwise_max(z[t] - t8, zero8);
      f16x8 mb = __builtin_elementwise_max(z[t + 1] - t8, zero8);
      lsA = dot8(ma, lsA);
      lsB = dot8(mb, lsB);
      lcA = dot8(__builtin_elementwise_min(ma * big8, one8), lcA);
      lcB = dot8(__builtin_elementwise_min(mb * big8, one8), lcB);
    }
    float ls = dpp_rsum(lsA + lsB);
    float lc = dpp_rsum(lcA + lcB);
    if (lc < 0.5f) break;
    float nt = tau + (ls - 1.0f) / lc;
    if (nt == tau) break;
    tau = nt;
  }
  return tau;
}

// ---------------------------------------------------------------- convert ---
struct ConvArgs {
  const float* src[8];
  u16* dst[8];
  int start4[9];   // exclusive prefix in float4 units
};

__global__ __launch_bounds__(256) void convert_all(ConvArgs a) {
  int idx = blockIdx.x * 256 + threadIdx.x;
  if (idx >= a.start4[8]) return;
  int s = 0;
#pragma unroll
  for (int i = 1; i < 8; ++i) s += (idx >= a.start4[i]) ? 1 : 0;
  int off = idx - a.start4[s];
  const float4* sp = (const float4*)a.src[s];
  float4 v = sp[off];
  ushort4 o;
  o.x = (u16)f2bf(v.x); o.y = (u16)f2bf(v.y);
  o.z = (u16)f2bf(v.z); o.w = (u16)f2bf(v.w);
  *(ushort4*)(a.dst[s] + (size_t)off * 4) = o;
}

__global__ __launch_bounds__(256) void zero_u16(u16* p, int n) {
  int i = blockIdx.x * 256 + threadIdx.x;
  if (i < n) p[i] = 0;
}

// ------------------------------------------------------------------- GEMM ---
// C[M,N] = A[M,K1] @ B[N,K1]^T (+ A2@B2^T if DUAL) + bias, then *escale,
// optional relu. m97 structure, global_load_lds width-16 staging.
// NOTE (R4/R5): these small-K GEMMs need >= 2 co-resident blocks/CU
// (>= 512 blocks on 256 CUs); TM=128 grids of 256 blocks regressed.
template<int BIAS, bool RELU, int OUTT, bool DUAL, int TM, int IN>
__global__ __launch_bounds__(256) void gemm_nt(
    const u16* __restrict__ A, int lda,
    const u16* __restrict__ B, int ldb,
    const u16* __restrict__ A2, int lda2,
    const u16* __restrict__ B2, int ldb2,
    int K1, int K2,
    const float* __restrict__ bias,
    void* __restrict__ C, int ldc, int N,
    float escale, size_t bzA, size_t bzB, size_t bzC)
{
  constexpr int MI = (TM == 128) ? 4 : 2;   // 16-row m-frags per wave
  __shared__ u16 As[TM * 32];
  __shared__ u16 Bs[128 * 32];

  const size_t zo = (size_t)blockIdx.z;
  A += zo * bzA;
  B += zo * bzB;
  u16*   C16 = (u16*)C + zo * bzC;
  float* C32 = (float*)C + zo * bzC;

  const int tid  = threadIdx.x;
  const int m0   = blockIdx.y * TM;
  const int n0   = blockIdx.x * 128;
  const int wave = tid >> 6, lane = tid & 63;
  const int lrow = lane & 15, quad = lane >> 4;
  const int wm   = (TM == 128) ? (wave & 1) * 64 : (wave >> 1) * 32;
  const int wn   = (TM == 128) ? (wave >> 1) * 64 : (wave & 1) * 64;

  f32x4 zero = {0.f, 0.f, 0.f, 0.f};
  f32x4 acc[MI][4];
#pragma unroll
  for (int i = 0; i < MI; ++i)
#pragma unroll
    for (int j = 0; j < 4; ++j) acc[i][j] = zero;

  const int KK = DUAL ? (K1 + K2) : K1;
  for (int k0 = 0; k0 < KK; k0 += 32) {
    const u16* Ap; const u16* Bp; int la, lb, kk;
    if (!DUAL || k0 < K1) { Ap = A;  Bp = B;  la = lda;  lb = ldb;  kk = k0; }
    else                  { Ap = A2; Bp = B2; la = lda2; lb = ldb2; kk = k0 - K1; }

#pragma unroll
    for (int i = 0; i < TM / 64; ++i) {       // A: TM*4 chunks of 16B
      int idx = i * 256 + tid;
      int row = idx >> 2, c8 = (idx & 3) * 8;
      async16(Ap + (size_t)(m0 + row) * la + kk + c8, &As[idx * 8]);
    }
#pragma unroll
    for (int i = 0; i < 2; ++i) {             // B: 512 chunks of 16B
      int idx = i * 256 + tid;
      int row = idx >> 2, c8 = (idx & 3) * 8;
      async16(Bp + (size_t)(n0 + row) * lb + kk + c8, &Bs[idx * 8]);
    }
    __syncthreads();

    bf16x8 af[MI], bfr[4];
#pragma unroll
    for (int i = 0; i < MI; ++i)
      af[i] = *(const bf16x8*)(&As[(wm + i * 16 + lrow) * 32 + quad * 8]);
#pragma unroll
    for (int j = 0; j < 4; ++j)
      bfr[j] = *(const bf16x8*)(&Bs[(wn + j * 16 + lrow) * 32 + quad * 8]);
#pragma unroll
    for (int i = 0; i < MI; ++i)
#pragma unroll
      for (int j = 0; j < 4; ++j) {
        if constexpr (IN == 0)
          acc[i][j] = __builtin_amdgcn_mfma_f32_16x16x32_bf16(af[i], bfr[j], acc[i][j], 0, 0, 0);
        else
          acc[i][j] = __builtin_amdgcn_mfma_f32_16x16x32_f16(
              __builtin_bit_cast(f16x8, af[i]), __builtin_bit_cast(f16x8, bfr[j]),
              acc[i][j], 0, 0, 0);
      }
    __syncthreads();
  }

  // epilogue: C layout col=lane&15, row=quad*4+r
#pragma unroll
  for (int i = 0; i < MI; ++i) {
#pragma unroll
    for (int j = 0; j < 4; ++j) {
      int gn = n0 + wn + j * 16 + lrow;
      if (gn >= N) continue;
      float bc = (BIAS == 1) ? bias[gn] : 0.0f;
#pragma unroll
      for (int r = 0; r < 4; ++r) {
        int gm = m0 + wm + i * 16 + quad * 4 + r;
        float v = acc[i][j][r] + bc;
        if (BIAS == 2) v += bias[gm];
        v *= escale;
        if (RELU) v = fmaxf(v, 0.0f);
        if (OUTT == 1)      C16[(size_t)gm * ldc + gn] = (u16)f2bf(v);
        else if (OUTT == 2) C16[(size_t)gm * ldc + gn] = f2h(v);
        else                C32[(size_t)gm * ldc + gn] = v;
      }
    }
  }
}

// --------------------------------------------- fused QKV projection GEMM ----
// One 1280-block launch computing Q (256 tiles), K (512), V^T (512).
// Same m97 TM=64 inner loop as gemm_nt; per-block runtime decode keeps the
// under-occupied Q phase packed (scheduler draws from the shared pool) and
// removes two inter-kernel drains. bmode: 1 = col bias, 2 = row bias.
struct QkvArgs {
  const u16* enc; const u16* mem;
  const u16* Wq;  const u16* Wk;  const u16* Wv;
  const float* bq; const float* bk; const float* bv;
  u16* Qb; u16* Kb; u16* Vtb;
};

__global__ __launch_bounds__(256) void qkv_gemm(QkvArgs a) {
  __shared__ u16 As[64 * 32];
  __shared__ u16 Bs[128 * 32];

  const int bid = blockIdx.x;
  const u16 *Ap, *Bp; const float* bias; u16* Cp;
  int m0, n0, ldc, bmode; float esc;
  if (bid < 256) {              // Q: [2048,1024] = enc @ Wq^T, 32x8 tiles
    int t = bid;       m0 = (t >> 3) * 64; n0 = (t & 7) * 128;
    Ap = a.enc; Bp = a.Wq; bias = a.bq; bmode = 1; esc = 1.0f / 32.0f;
    Cp = a.Qb;  ldc = 1024;
  } else if (bid < 768) {       // K: [4096,1024] = mem @ Wk^T, 64x8 tiles
    int t = bid - 256; m0 = (t >> 3) * 64; n0 = (t & 7) * 128;
    Ap = a.mem; Bp = a.Wk; bias = a.bk; bmode = 1; esc = 1.0f;
    Cp = a.Kb;  ldc = 1024;
  } else {                      // V^T: [1024,4096] = Wv @ mem^T, 16x32 tiles
    int t = bid - 768; m0 = (t >> 5) * 64; n0 = (t & 31) * 128;
    Ap = a.Wv;  Bp = a.mem; bias = a.bv; bmode = 2; esc = 1.0f;
    Cp = a.Vtb; ldc = 4096;
  }

  const int tid  = threadIdx.x;
  const int wave = tid >> 6, lane = tid & 63;
  const int lrow = lane & 15, quad = lane >> 4;
  const int wm   = (wave >> 1) * 32;
  const int wn   = (wave & 1) * 64;

  f32x4 zero = {0.f, 0.f, 0.f, 0.f};
  f32x4 acc[2][4];
#pragma unroll
  for (int i = 0; i < 2; ++i)
#pragma unroll
    for (int j = 0; j < 4; ++j) acc[i][j] = zero;

  for (int k0 = 0; k0 < 1024; k0 += 32) {
    {                                         // A: 256 chunks of 16B
      int row = tid >> 2, c8 = (tid & 3) * 8;
      async16(Ap + (size_t)(m0 + row) * 1024 + k0 + c8, &As[tid * 8]);
    }
#pragma unroll
    for (int i = 0; i < 2; ++i) {             // B: 512 chunks of 16B
      int idx = i * 256 + tid;
      int row = idx >> 2, c8 = (idx & 3) * 8;
      async16(Bp + (size_t)(n0 + row) * 1024 + k0 + c8, &Bs[idx * 8]);
    }
    __syncthreads();

    bf16x8 af[2], bfr[4];
#pragma unroll
    for (int i = 0; i < 2; ++i)
      af[i] = *(const bf16x8*)(&As[(wm + i * 16 + lrow) * 32 + quad * 8]);
#pragma unroll
    for (int j = 0; j < 4; ++j)
      bfr[j] = *(const bf16x8*)(&Bs[(wn + j * 16 + lrow) * 32 + quad * 8]);
#pragma unroll
    for (int i = 0; i < 2; ++i)
#pragma unroll
      for (int j = 0; j < 4; ++j)
        acc[i][j] = __builtin_amdgcn_mfma_f32_16x16x32_bf16(af[i], bfr[j], acc[i][j], 0, 0, 0);
    __syncthreads();
  }

#pragma unroll
  for (int i = 0; i < 2; ++i) {
#pragma unroll
    for (int j = 0; j < 4; ++j) {
      int gn = n0 + wn + j * 16 + lrow;
      float bc = (bmode == 1) ? bias[gn] : 0.0f;
#pragma unroll
      for (int r = 0; r < 4; ++r) {
        int gm = m0 + wm + i * 16 + quad * 4 + r;
        float v = acc[i][j][r] + bc;
        if (bmode == 2) v += bias[gm];
        v *= esc;
        Cp[(size_t)gm * ldc + gn] = f2h(v);
      }
    }
  }
}

// ------------------------------------------------- standalone sparsemax -----
__global__ __launch_bounds__(256) void sparsemax_rows(u16* __restrict__ Sp) {
  const int wave = threadIdx.x >> 6, lane = threadIdx.x & 63;
  const int wid  = blockIdx.x * 4 + wave;
  const f16x8 zero8 = {(f16)0, (f16)0, (f16)0, (f16)0, (f16)0, (f16)0, (f16)0, (f16)0};

#pragma unroll 1
  for (int rr = 0; rr < 2; ++rr) {
    const size_t row = (size_t)wid * 2 + rr;
    f16* Srow = (f16*)Sp + row * 4096;
    f16x8 z[8];
#pragma unroll
    for (int t = 0; t < 8; ++t)
      z[t] = *(const f16x8*)(Srow + t * 512 + lane * 8);

    float tau = solve_tau(z);

    f16 tq = (f16)tau;
    f16x8 t8 = {tq, tq, tq, tq, tq, tq, tq, tq};
#pragma unroll
    for (int t = 0; t < 8; ++t)
      *(f16x8*)(Srow + t * 512 + lane * 8) =
          __builtin_elementwise_max(z[t] - t8, zero8);
  }
}

// ------------------------------------------------- fused attention (R7) -----
// Key-half staging (65.8 KB LDS -> 2 blocks/CU = 32 waves, wave cap).
// R7 version restored verbatim: R8's deeper prefetch blew the 64-VGPR cap and
// spilled to scratch (WRITE_SIZE 4 MB -> 68 MB). This structure is at its
// measured latency floor (~303 us) — do not micro-tune further.
__global__ __launch_bounds__(1024, 8) void attn_sparsemax2(
    const f16* __restrict__ Q,    // [2048][1024] f16 (pre-scaled)
    const f16* __restrict__ Km,   // [4096][1024] f16
    const f16* __restrict__ Vt,   // [1024][4096] f16 (V transposed)
    u16* __restrict__ AO)         // [2048][1024] bf16
{
  constexpr int HROW = 2048 + 8;                 // f16 per row, half-keys + pad
  __shared__ __align__(16) char ldsbuf[16 * HROW * 2];   // 65,792 B
  f16*   S    = (f16*)ldsbuf;
  float* Ored = (float*)ldsbuf;                  // [kseg][dhg][256], aliased

  const int id    = blockIdx.x;
  const int head  = (id & 7) * 2 + ((id >> 3) >> 7);
  const int qblk  = (id >> 3) & 127;
  const int qbase = qblk * 16;
  const int tid   = threadIdx.x;
  const int wave  = tid >> 6, lane = tid & 63;
  const int lrow  = lane & 15, quad = lane >> 4;

  const f16* qp = Q + (size_t)(qbase + lrow) * 1024 + head * 64 + quad * 8;
  f16x8 qf0 = *(const f16x8*)qp;
  f16x8 qf1 = *(const f16x8*)(qp + 32);

  f16x8 z[8];

  // ---- QK^T in two key-halves; z row crosses the restage in registers ----
#pragma unroll
  for (int H = 0; H < 2; ++H) {
    const f16* kpb = Km + (size_t)(H * 2048 + wave * 128 + lrow) * 1024
                        + head * 64 + quad * 8;
    f16x8 kf0n = *(const f16x8*)kpb;
    f16x8 kf1n = *(const f16x8*)(kpb + 32);
#pragma unroll
    for (int kt = 0; kt < 8; ++kt) {
      f16x8 kf0 = kf0n, kf1 = kf1n;
      if (kt < 7) {
        kpb += (size_t)16 * 1024;
        kf0n = *(const f16x8*)kpb;
        kf1n = *(const f16x8*)(kpb + 32);
      }
      f32x4 sc = {0.f, 0.f, 0.f, 0.f};
      __builtin_amdgcn_s_setprio(1);
      sc = __builtin_amdgcn_mfma_f32_16x16x32_f16(qf0, kf0, sc, 0, 0, 0);
      sc = __builtin_amdgcn_mfma_f32_16x16x32_f16(qf1, kf1, sc, 0, 0, 0);
      __builtin_amdgcn_s_setprio(0);
      int lk = wave * 128 + kt * 16;             // local (in-half) key col
#pragma unroll
      for (int r = 0; r < 4; ++r)
        S[(quad * 4 + r) * HROW + lk + lrow] = (f16)sc[r];
    }
    __syncthreads();
#pragma unroll
    for (int t = 0; t < 4; ++t)
      z[H * 4 + t] = *(const f16x8*)(&S[wave * HROW + t * 512 + lane * 8]);
    __syncthreads();   // all reads done before tile is overwritten
  }

  // ---- candidate-compact sparsemax solve ----
  float m;
  {
    f16x8 mx = z[0];
#pragma unroll
    for (int t = 1; t < 8; ++t) mx = __builtin_elementwise_max(mx, z[t]);
    m = dpp_rmax(hmax8(mx));
  }
  float tau;
  f16* cbuf = &S[wave * HROW];            // own strip: exclusive until P-write
  f16  thr_h = (f16)(m - 1.01f);          // margin so RNE stays <= m-1
  bool compact_ok = ((float)thr_h <= m - 1.0f);
  int cnt = 0;
  if (compact_ok) {
#pragma unroll
    for (int t = 0; t < 8; ++t) {
#pragma unroll
      for (int j = 0; j < 8; ++j) {
        bool c = (z[t][j] > thr_h);
        unsigned long long mk = __ballot(c);
        if (mk) {                          // wave-uniform skip (most elems)
          if (c) {
            int slot = cnt + __builtin_amdgcn_mbcnt_hi(
                (unsigned)(mk >> 32),
                __builtin_amdgcn_mbcnt_lo((unsigned)mk, 0));
            if (slot < 64) cbuf[slot] = z[t][j];
          }
          cnt += (int)__popcll(mk);
        }
      }
    }
  }
  if (compact_ok && cnt <= 64) {
    asm volatile("s_waitcnt lgkmcnt(0)" ::: "memory");
    f16 craw = cbuf[lane];
    const f16 nbig = (f16)-65504.0f;
    f16 cand = (lane < cnt) ? craw : nbig;
    tau = m - 1.0f;
#pragma unroll 1
    for (int it = 0; it < 8; ++it) {
      // f16 elementwise math matches the full-row path exactly
      f16 tq = (f16)tau;
      f16 dh = cand - tq;
      f16 rh = (dh > (f16)0) ? dh : (f16)0;
      f16 ih = rh * (f16)65504.0f;
      ih = (ih < (f16)1) ? ih : (f16)1;
      float ls = dpp_rsum((float)rh);
      float lc = dpp_rsum((float)ih);
      if (lc < 0.5f) break;
      float nt = tau + (ls - 1.0f) / lc;
      if (nt == tau) break;
      tau = nt;
    }
  } else {
    tau = solve_tau(z);                    // full-row fallback (rare)
  }

  const f16 tq = (f16)tau;
  const f16x8 t8 = {tq, tq, tq, tq, tq, tq, tq, tq};
  const f16x8 zero8 = {(f16)0, (f16)0, (f16)0, (f16)0, (f16)0, (f16)0, (f16)0, (f16)0};

  const int dhg = wave & 3, kseg = wave >> 2;    // 4 dh-groups x 4 k-segments
  f32x4 oacc0 = {0.f, 0.f, 0.f, 0.f};
  f32x4 oacc1 = {0.f, 0.f, 0.f, 0.f};
  const f16* vbase = Vt + (size_t)(head * 64 + dhg * 16 + lrow) * 4096
                        + kseg * 512 + quad * 8;
  const f16* prow  = &S[lrow * HROW + kseg * 512 + quad * 8];

  // ---- P write + PV, per key-half (accumulators carry across halves) ----
#pragma unroll
  for (int H = 0; H < 2; ++H) {
    const f16* vrow = vbase + H * 2048;
    f16x8 vf0n = *(const f16x8*)(vrow);
    f16x8 vf1n = *(const f16x8*)(vrow + 32);
#pragma unroll
    for (int t = 0; t < 4; ++t)
      *(f16x8*)(&S[wave * HROW + t * 512 + lane * 8]) =
          __builtin_elementwise_max(z[H * 4 + t] - t8, zero8);
    __syncthreads();
#pragma unroll
    for (int kt = 0; kt < 16; kt += 2) {
      f16x8 vf0 = vf0n, vf1 = vf1n;
      if (kt < 14) {
        vf0n = *(const f16x8*)(vrow + (kt + 2) * 32);
        vf1n = *(const f16x8*)(vrow + (kt + 2) * 32 + 32);
      }
      f16x8 pf0 = *(const f16x8*)(prow + kt * 32);
      f16x8 pf1 = *(const f16x8*)(prow + kt * 32 + 32);
      __builtin_amdgcn_s_setprio(1);
      oacc0 = __builtin_amdgcn_mfma_f32_16x16x32_f16(pf0, vf0, oacc0, 0, 0, 0);
      oacc1 = __builtin_amdgcn_mfma_f32_16x16x32_f16(pf1, vf1, oacc1, 0, 0, 0);
      __builtin_amdgcn_s_setprio(0);
    }
    __syncthreads();   // all P reads done (H=1: before Ored aliases S)
  }
  f32x4 oacc = oacc0 + oacc1;

  // ---- cross-kseg reduction via aliased Ored, then AO store ----
  float* orp = &Ored[(kseg * 4 + dhg) * 256];
#pragma unroll
  for (int r = 0; r < 4; ++r) orp[(quad * 4 + r) * 16 + lrow] = oacc[r];
  __syncthreads();
  if (kseg == 0) {
#pragma unroll
    for (int r = 0; r < 4; ++r) {
      int idx = (quad * 4 + r) * 16 + lrow;
      float v = oacc[r] + Ored[(1 * 4 + dhg) * 256 + idx]
                        + Ored[(2 * 4 + dhg) * 256 + idx]
                        + Ored[(3 * 4 + dhg) * 256 + idx];
      AO[(size_t)(qbase + quad * 4 + r) * 1024 + head * 64 + dhg * 16 + lrow] = (u16)f2bf(v);
    }
  }
}

// ---------------------------------------------------------------- launcher --
extern "C" void kernel_launch(void* const* d_in, const int* in_sizes, int n_in,
                              void* d_out, int out_size, void* d_ws, size_t ws_size,
                              hipStream_t stream) {
  const float* enc = (const float*)d_in[0];
  const float* mem = (const float*)d_in[1];
  const float* Wq  = (const float*)d_in[2];
  const float* bq  = (const float*)d_in[3];
  const float* Wk  = (const float*)d_in[4];
  const float* bk  = (const float*)d_in[5];
  const float* Wv  = (const float*)d_in[6];
  const float* bv  = (const float*)d_in[7];
  const float* Wo  = (const float*)d_in[8];
  const float* bo  = (const float*)d_in[9];
  const float* W1  = (const float*)d_in[10];
  const float* b1  = (const float*)d_in[11];
  const float* W2  = (const float*)d_in[12];
  const float* b2  = (const float*)d_in[13];

  char* ws = (char*)d_ws;
  const size_t MB = 1024 * 1024;
  u16* enc_bf = (u16*)(ws + 0 * MB);   // 2048x1024 bf16
  u16* mem_bf = (u16*)(ws + 4 * MB);   // 4096x1024 bf16
  u16* Wq_bf  = (u16*)(ws + 12 * MB);
  u16* Wk_bf  = (u16*)(ws + 14 * MB);
  u16* Wv_bf  = (u16*)(ws + 16 * MB);
  u16* Wo_bf  = (u16*)(ws + 18 * MB);
  u16* W1_bf  = (u16*)(ws + 20 * MB);  // 4096x2048
  u16* W2_bf  = (u16*)(ws + 36 * MB);  // 1024x4096 (padded from 1000)
  u16* Qb     = (u16*)(ws + 46 * MB);  // 2048x1024 f16 (pre-scaled by 1/32)
  u16* Kb     = (u16*)(ws + 50 * MB);  // 4096x1024 f16
  u16* Vtb    = (u16*)(ws + 58 * MB);  // 1024x4096 f16 (V^T)
  u16* AO     = (u16*)(ws + 66 * MB);  // 2048x1024 bf16
  u16* OUT    = (u16*)(ws + 70 * MB);  // 2048x1024 bf16
  u16* Hh     = (u16*)(ws + 74 * MB);  // 2048x4096 bf16
  u16* Sbuf   = (u16*)(ws + 96 * MB);  // 16x2048x4096 f16 = 256 MB (split path)

  const bool split = ws_size >= (size_t)360 * MB;  // constant per harness

  ConvArgs ca;
  const float* srcs[8] = {enc, mem, Wq, Wk, Wv, Wo, W1, W2};
  u16* dsts[8] = {enc_bf, mem_bf, Wq_bf, Wk_bf, Wv_bf, Wo_bf, W1_bf, W2_bf};
  int sizes[8] = {2048 * 1024, 4096 * 1024, 1024 * 1024, 1024 * 1024,
                  1024 * 1024, 1024 * 1024, 4096 * 2048, 1000 * 4096};
  int start = 0;
  for (int i = 0; i < 8; ++i) {
    ca.src[i] = srcs[i]; ca.dst[i] = dsts[i];
    ca.start4[i] = start; start += sizes[i] / 4;
  }
  ca.start4[8] = start;
  convert_all<<<(start + 255) / 256, 256, 0, stream>>>(ca);
  zero_u16<<<(24 * 4096 + 255) / 256, 256, 0, stream>>>(W2_bf + 1000 * 4096, 24 * 4096);

  // Q, K, V^T in one 1280-block launch (keeps CUs packed, drops 2 drains)
  QkvArgs qa;
  qa.enc = enc_bf; qa.mem = mem_bf;
  qa.Wq = Wq_bf; qa.Wk = Wk_bf; qa.Wv = Wv_bf;
  qa.bq = bq; qa.bk = bk; qa.bv = bv;
  qa.Qb = Qb; qa.Kb = Kb; qa.Vtb = Vtb;
  qkv_gemm<<<1280, 256, 0, stream>>>(qa);

  if (split) {
    gemm_nt<0, false, 2, false, 128, 1><<<dim3(32, 16, 16), 256, 0, stream>>>(
        Qb, 1024, Kb, 1024, nullptr, 0, nullptr, 0, 64, 0, nullptr,
        Sbuf, 4096, 4096, 1.0f, 64, 64, (size_t)2048 * 4096);
    sparsemax_rows<<<4096, 256, 0, stream>>>(Sbuf);
    gemm_nt<0, false, 1, false, 64, 1><<<dim3(1, 32, 16), 256, 0, stream>>>(
        Sbuf, 4096, Vtb, 4096, nullptr, 0, nullptr, 0, 4096, 0, nullptr,
        AO, 1024, 64, 1.0f, (size_t)2048 * 4096, (size_t)64 * 4096, 64);
  } else {
    attn_sparsemax2<<<2048, 1024, 0, stream>>>(
        (const f16*)Qb, (const f16*)Kb, (const f16*)Vtb, AO);
  }

  // OUT = AO @ Wo^T + bo (bf16 out)  [TM=64: 256 blocks]
  gemm_nt<1, false, 1, false, 64, 0><<<dim3(8, 32), 256, 0, stream>>>(
      AO, 1024, Wo_bf, 1024, nullptr, 0, nullptr, 0, 1024, 0, bo,
      OUT, 1024, 1024, 1.0f, 0, 0, 0);
  // H = relu(enc@W1a^T + OUT@W1b^T + b1)  [TM=128: 512 blocks]
  gemm_nt<1, true, 1, true, 128, 0><<<dim3(32, 16), 256, 0, stream>>>(
      enc_bf, 1024, W1_bf, 2048, OUT, 1024, W1_bf + 1024, 2048, 1024, 1024, b1,
      Hh, 4096, 4096, 1.0f, 0, 0, 0);
  // out = H @ W2^T + b2 (fp32 out, N=1000)  [TM=64: 256 blocks]
  gemm_nt<1, false, 0, false, 64, 0><<<dim3(8, 32), 256, 0, stream>>>(
      Hh, 4096, W2_bf, 4096, nullptr, 0, nullptr, 0, 4096, 0, b2,
      d_out, 1000, 1000, 1.0f, 0, 0, 0);
}

// Round 10
// 581.282 us; speedup vs baseline: 1.0887x; 1.0335x over previous
//
#include <hip/hip_runtime.h>
#include <stdint.h>
#include <stddef.h>

typedef unsigned short u16;
using f16    = _Float16;
using f16x2  = __attribute__((ext_vector_type(2))) _Float16;
using f16x8  = __attribute__((ext_vector_type(8))) _Float16;
using bf16x8 = __attribute__((ext_vector_type(8))) short;
using f32x4  = __attribute__((ext_vector_type(4))) float;

__device__ __forceinline__ short f2bf(float f) {
  uint32_t u = __builtin_bit_cast(uint32_t, f);
  u += 0x7FFFu + ((u >> 16) & 1u);   // RNE
  return (short)(u >> 16);
}
__device__ __forceinline__ u16 f2h(float f) {
  return __builtin_bit_cast(u16, (f16)f);
}

// async global->LDS, 16B per lane; LDS dest must be wave-contiguous (m97/m104)
typedef const __attribute__((address_space(1))) void* gas_t;
typedef __attribute__((address_space(3))) void* las_t;
__device__ __forceinline__ void async16(const void* g, void* l) {
  __builtin_amdgcn_global_load_lds((gas_t)g, (las_t)l, 16, 0, 0);
}

// sum of 8 f16 lanes into fp32 acc via 4x v_dot2_f32_f16
__device__ __forceinline__ float dot8(f16x8 v, float acc) {
  union { f16x8 v8; f16x2 v2[4]; } u;
  u.v8 = v;
  const f16x2 one2 = {(f16)1, (f16)1};
  acc = __builtin_amdgcn_fdot2(u.v2[0], one2, acc, false);
  acc = __builtin_amdgcn_fdot2(u.v2[1], one2, acc, false);
  acc = __builtin_amdgcn_fdot2(u.v2[2], one2, acc, false);
  acc = __builtin_amdgcn_fdot2(u.v2[3], one2, acc, false);
  return acc;
}
// horizontal max of f16x8 -> float
__device__ __forceinline__ float hmax8(f16x8 v) {
  union { f16x8 v8; f16x2 v2[4]; } u;
  u.v8 = v;
  f16x2 a = __builtin_elementwise_max(u.v2[0], u.v2[1]);
  f16x2 b = __builtin_elementwise_max(u.v2[2], u.v2[3]);
  f16x2 c = __builtin_elementwise_max(a, b);
  return fmaxf((float)c[0], (float)c[1]);
}

// ---- wave64 reductions via DPP (VALU pipe, no LDS) -------------------------
__device__ __forceinline__ float dpp_rsum(float x) {
  int v;
  v = __builtin_amdgcn_update_dpp(0, __builtin_bit_cast(int, x), 0xB1, 0xf, 0xf, false);
  x += __builtin_bit_cast(float, v);
  v = __builtin_amdgcn_update_dpp(0, __builtin_bit_cast(int, x), 0x4E, 0xf, 0xf, false);
  x += __builtin_bit_cast(float, v);
  v = __builtin_amdgcn_update_dpp(0, __builtin_bit_cast(int, x), 0x141, 0xf, 0xf, false);
  x += __builtin_bit_cast(float, v);
  v = __builtin_amdgcn_update_dpp(0, __builtin_bit_cast(int, x), 0x140, 0xf, 0xf, false);
  x += __builtin_bit_cast(float, v);
  v = __builtin_amdgcn_update_dpp(0, __builtin_bit_cast(int, x), 0x142, 0xa, 0xf, false);
  x += __builtin_bit_cast(float, v);
  v = __builtin_amdgcn_update_dpp(0, __builtin_bit_cast(int, x), 0x143, 0xc, 0xf, false);
  x += __builtin_bit_cast(float, v);
  return __builtin_bit_cast(float, __builtin_amdgcn_readlane(__builtin_bit_cast(int, x), 63));
}
__device__ __forceinline__ float dpp_rmax(float x) {
  const int NINF = 0xFF800000;
  int v;
  v = __builtin_amdgcn_update_dpp(NINF, __builtin_bit_cast(int, x), 0xB1, 0xf, 0xf, false);
  x = fmaxf(x, __builtin_bit_cast(float, v));
  v = __builtin_amdgcn_update_dpp(NINF, __builtin_bit_cast(int, x), 0x4E, 0xf, 0xf, false);
  x = fmaxf(x, __builtin_bit_cast(float, v));
  v = __builtin_amdgcn_update_dpp(NINF, __builtin_bit_cast(int, x), 0x141, 0xf, 0xf, false);
  x = fmaxf(x, __builtin_bit_cast(float, v));
  v = __builtin_amdgcn_update_dpp(NINF, __builtin_bit_cast(int, x), 0x140, 0xf, 0xf, false);
  x = fmaxf(x, __builtin_bit_cast(float, v));
  v = __builtin_amdgcn_update_dpp(NINF, __builtin_bit_cast(int, x), 0x142, 0xa, 0xf, false);
  x = fmaxf(x, __builtin_bit_cast(float, v));
  v = __builtin_amdgcn_update_dpp(NINF, __builtin_bit_cast(int, x), 0x143, 0xc, 0xf, false);
  x = fmaxf(x, __builtin_bit_cast(float, v));
  return __builtin_bit_cast(float, __builtin_amdgcn_readlane(__builtin_bit_cast(int, x), 63));
}

// ---- full-row sparsemax solver (fallback + standalone path) ----------------
__device__ __forceinline__ float solve_tau(const f16x8* z) {
  const f16 bg = (f16)65504.0f;
  const f16x8 big8  = {bg, bg, bg, bg, bg, bg, bg, bg};
  const f16x8 one8  = {(f16)1, (f16)1, (f16)1, (f16)1, (f16)1, (f16)1, (f16)1, (f16)1};
  const f16x8 zero8 = {(f16)0, (f16)0, (f16)0, (f16)0, (f16)0, (f16)0, (f16)0, (f16)0};

  float sA = 0.f, sB = 0.f;
  f16x8 mx = z[0];
#pragma unroll
  for (int t = 0; t < 8; t += 2) {
    sA = dot8(z[t], sA);
    sB = dot8(z[t + 1], sB);
  }
#pragma unroll
  for (int t = 1; t < 8; ++t) mx = __builtin_elementwise_max(mx, z[t]);

  float s = dpp_rsum(sA + sB);
  float m = dpp_rmax(hmax8(mx));

  float tau = fmaxf((s - 1.0f) * (1.0f / 4096.0f), m - 1.0f);

#pragma unroll 1
  for (int it = 0; it < 6; ++it) {
    f16 tq = (f16)tau;
    f16x8 t8 = {tq, tq, tq, tq, tq, tq, tq, tq};
    float lsA = 0.f, lsB = 0.f, lcA = 0.f, lcB = 0.f;
#pragma unroll
    for (int t = 0; t < 8; t += 2) {
      f16x8 ma = __builtin_elementwise_max(z[t] - t8, zero8);
      f16x8 mb = __builtin_elementwise_max(z[t + 1] - t8, zero8);
      lsA = dot8(ma, lsA);
      lsB = dot8(mb, lsB);
      lcA = dot8(__builtin_elementwise_min(ma * big8, one8), lcA);
      lcB = dot8(__builtin_elementwise_min(mb * big8, one8), lcB);
    }
    float ls = dpp_rsum(lsA + lsB);
    float lc = dpp_rsum(lcA + lcB);
    if (lc < 0.5f) break;
    float nt = tau + (ls - 1.0f) / lc;
    if (nt == tau) break;
    tau = nt;
  }
  return tau;
}

// ---------------------------------------------------------------- convert ---
// Also zeroes the W2 padding tail (folded in: one fewer launch/drain).
struct ConvArgs {
  const float* src[8];
  u16* dst[8];
  int start4[9];   // exclusive prefix in float4 units
  u16* zdst; int zn4;   // zero-fill tail, in 4-u16 units
};

__global__ __launch_bounds__(256) void convert_all(ConvArgs a) {
  int idx = blockIdx.x * 256 + threadIdx.x;
  int tot = a.start4[8];
  if (idx >= tot) {
    int zi = idx - tot;
    if (zi < a.zn4) {
      ushort4 zz = {0, 0, 0, 0};
      *(ushort4*)(a.zdst + (size_t)zi * 4) = zz;
    }
    return;
  }
  int s = 0;
#pragma unroll
  for (int i = 1; i < 8; ++i) s += (idx >= a.start4[i]) ? 1 : 0;
  int off = idx - a.start4[s];
  const float4* sp = (const float4*)a.src[s];
  float4 v = sp[off];
  ushort4 o;
  o.x = (u16)f2bf(v.x); o.y = (u16)f2bf(v.y);
  o.z = (u16)f2bf(v.z); o.w = (u16)f2bf(v.w);
  *(ushort4*)(a.dst[s] + (size_t)off * 4) = o;
}

// ------------------------------------------------------------------- GEMM ---
// C[M,N] = A[M,K1] @ B[N,K1]^T (+ A2@B2^T if DUAL) + bias, then *escale,
// optional relu. m97 structure, global_load_lds width-16 staging.
// TN=64 gives a 64x64 tile for M=2048 shapes -> 512 blocks = 2 blocks/CU
// (R4/R5: occupancy term dominates staging efficiency at these small shapes).
template<int BIAS, bool RELU, int OUTT, bool DUAL, int TM, int IN, int TN = 128>
__global__ __launch_bounds__(256) void gemm_nt(
    const u16* __restrict__ A, int lda,
    const u16* __restrict__ B, int ldb,
    const u16* __restrict__ A2, int lda2,
    const u16* __restrict__ B2, int ldb2,
    int K1, int K2,
    const float* __restrict__ bias,
    void* __restrict__ C, int ldc, int N,
    float escale, size_t bzA, size_t bzB, size_t bzC)
{
  static_assert(TM == 64 || TN == 128, "TN=64 only with TM=64");
  constexpr int MI = (TM == 128) ? 4 : 2;   // 16-row m-frags per wave
  constexpr int NI = TN / 32;               // 16-col n-frags per wave (4 or 2)
  __shared__ u16 As[TM * 32];
  __shared__ u16 Bs[TN * 32];

  const size_t zo = (size_t)blockIdx.z;
  A += zo * bzA;
  B += zo * bzB;
  u16*   C16 = (u16*)C + zo * bzC;
  float* C32 = (float*)C + zo * bzC;

  const int tid  = threadIdx.x;
  const int m0   = blockIdx.y * TM;
  const int n0   = blockIdx.x * TN;
  const int wave = tid >> 6, lane = tid & 63;
  const int lrow = lane & 15, quad = lane >> 4;
  const int wm   = (TM == 128) ? (wave & 1) * 64 : (wave >> 1) * 32;
  const int wn   = (TM == 128) ? (wave >> 1) * 64 : (wave & 1) * (TN / 2);

  f32x4 zero = {0.f, 0.f, 0.f, 0.f};
  f32x4 acc[MI][NI];
#pragma unroll
  for (int i = 0; i < MI; ++i)
#pragma unroll
    for (int j = 0; j < NI; ++j) acc[i][j] = zero;

  const int KK = DUAL ? (K1 + K2) : K1;
  for (int k0 = 0; k0 < KK; k0 += 32) {
    const u16* Ap; const u16* Bp; int la, lb, kk;
    if (!DUAL || k0 < K1) { Ap = A;  Bp = B;  la = lda;  lb = ldb;  kk = k0; }
    else                  { Ap = A2; Bp = B2; la = lda2; lb = ldb2; kk = k0 - K1; }

#pragma unroll
    for (int i = 0; i < TM / 64; ++i) {       // A: TM*4 chunks of 16B
      int idx = i * 256 + tid;
      int row = idx >> 2, c8 = (idx & 3) * 8;
      async16(Ap + (size_t)(m0 + row) * la + kk + c8, &As[idx * 8]);
    }
#pragma unroll
    for (int i = 0; i < TN / 64; ++i) {       // B: TN*4 chunks of 16B
      int idx = i * 256 + tid;
      int row = idx >> 2, c8 = (idx & 3) * 8;
      async16(Bp + (size_t)(n0 + row) * lb + kk + c8, &Bs[idx * 8]);
    }
    __syncthreads();

    bf16x8 af[MI], bfr[NI];
#pragma unroll
    for (int i = 0; i < MI; ++i)
      af[i] = *(const bf16x8*)(&As[(wm + i * 16 + lrow) * 32 + quad * 8]);
#pragma unroll
    for (int j = 0; j < NI; ++j)
      bfr[j] = *(const bf16x8*)(&Bs[(wn + j * 16 + lrow) * 32 + quad * 8]);
#pragma unroll
    for (int i = 0; i < MI; ++i)
#pragma unroll
      for (int j = 0; j < NI; ++j) {
        if constexpr (IN == 0)
          acc[i][j] = __builtin_amdgcn_mfma_f32_16x16x32_bf16(af[i], bfr[j], acc[i][j], 0, 0, 0);
        else
          acc[i][j] = __builtin_amdgcn_mfma_f32_16x16x32_f16(
              __builtin_bit_cast(f16x8, af[i]), __builtin_bit_cast(f16x8, bfr[j]),
              acc[i][j], 0, 0, 0);
      }
    __syncthreads();
  }

  // epilogue: C layout col=lane&15, row=quad*4+r
#pragma unroll
  for (int i = 0; i < MI; ++i) {
#pragma unroll
    for (int j = 0; j < NI; ++j) {
      int gn = n0 + wn + j * 16 + lrow;
      if (gn >= N) continue;
      float bc = (BIAS == 1) ? bias[gn] : 0.0f;
#pragma unroll
      for (int r = 0; r < 4; ++r) {
        int gm = m0 + wm + i * 16 + quad * 4 + r;
        float v = acc[i][j][r] + bc;
        if (BIAS == 2) v += bias[gm];
        v *= escale;
        if (RELU) v = fmaxf(v, 0.0f);
        if (OUTT == 1)      C16[(size_t)gm * ldc + gn] = (u16)f2bf(v);
        else if (OUTT == 2) C16[(size_t)gm * ldc + gn] = f2h(v);
        else                C32[(size_t)gm * ldc + gn] = v;
      }
    }
  }
}

// --------------------------------------------- fused QKV projection GEMM ----
// One 1280-block launch computing Q (256 tiles), K (512), V^T (512).
struct QkvArgs {
  const u16* enc; const u16* mem;
  const u16* Wq;  const u16* Wk;  const u16* Wv;
  const float* bq; const float* bk; const float* bv;
  u16* Qb; u16* Kb; u16* Vtb;
};

__global__ __launch_bounds__(256) void qkv_gemm(QkvArgs a) {
  __shared__ u16 As[64 * 32];
  __shared__ u16 Bs[128 * 32];

  const int bid = blockIdx.x;
  const u16 *Ap, *Bp; const float* bias; u16* Cp;
  int m0, n0, ldc, bmode; float esc;
  if (bid < 256) {              // Q: [2048,1024] = enc @ Wq^T, 32x8 tiles
    int t = bid;       m0 = (t >> 3) * 64; n0 = (t & 7) * 128;
    Ap = a.enc; Bp = a.Wq; bias = a.bq; bmode = 1; esc = 1.0f / 32.0f;
    Cp = a.Qb;  ldc = 1024;
  } else if (bid < 768) {       // K: [4096,1024] = mem @ Wk^T, 64x8 tiles
    int t = bid - 256; m0 = (t >> 3) * 64; n0 = (t & 7) * 128;
    Ap = a.mem; Bp = a.Wk; bias = a.bk; bmode = 1; esc = 1.0f;
    Cp = a.Kb;  ldc = 1024;
  } else {                      // V^T: [1024,4096] = Wv @ mem^T, 16x32 tiles
    int t = bid - 768; m0 = (t >> 5) * 64; n0 = (t & 31) * 128;
    Ap = a.Wv;  Bp = a.mem; bias = a.bv; bmode = 2; esc = 1.0f;
    Cp = a.Vtb; ldc = 4096;
  }

  const int tid  = threadIdx.x;
  const int wave = tid >> 6, lane = tid & 63;
  const int lrow = lane & 15, quad = lane >> 4;
  const int wm   = (wave >> 1) * 32;
  const int wn   = (wave & 1) * 64;

  f32x4 zero = {0.f, 0.f, 0.f, 0.f};
  f32x4 acc[2][4];
#pragma unroll
  for (int i = 0; i < 2; ++i)
#pragma unroll
    for (int j = 0; j < 4; ++j) acc[i][j] = zero;

  for (int k0 = 0; k0 < 1024; k0 += 32) {
    {                                         // A: 256 chunks of 16B
      int row = tid >> 2, c8 = (tid & 3) * 8;
      async16(Ap + (size_t)(m0 + row) * 1024 + k0 + c8, &As[tid * 8]);
    }
#pragma unroll
    for (int i = 0; i < 2; ++i) {             // B: 512 chunks of 16B
      int idx = i * 256 + tid;
      int row = idx >> 2, c8 = (idx & 3) * 8;
      async16(Bp + (size_t)(n0 + row) * 1024 + k0 + c8, &Bs[idx * 8]);
    }
    __syncthreads();

    bf16x8 af[2], bfr[4];
#pragma unroll
    for (int i = 0; i < 2; ++i)
      af[i] = *(const bf16x8*)(&As[(wm + i * 16 + lrow) * 32 + quad * 8]);
#pragma unroll
    for (int j = 0; j < 4; ++j)
      bfr[j] = *(const bf16x8*)(&Bs[(wn + j * 16 + lrow) * 32 + quad * 8]);
#pragma unroll
    for (int i = 0; i < 2; ++i)
#pragma unroll
      for (int j = 0; j < 4; ++j)
        acc[i][j] = __builtin_amdgcn_mfma_f32_16x16x32_bf16(af[i], bfr[j], acc[i][j], 0, 0, 0);
    __syncthreads();
  }

#pragma unroll
  for (int i = 0; i < 2; ++i) {
#pragma unroll
    for (int j = 0; j < 4; ++j) {
      int gn = n0 + wn + j * 16 + lrow;
      float bc = (bmode == 1) ? bias[gn] : 0.0f;
#pragma unroll
      for (int r = 0; r < 4; ++r) {
        int gm = m0 + wm + i * 16 + quad * 4 + r;
        float v = acc[i][j][r] + bc;
        if (bmode == 2) v += bias[gm];
        v *= esc;
        Cp[(size_t)gm * ldc + gn] = f2h(v);
      }
    }
  }
}

// ------------------------------------------------- standalone sparsemax -----
__global__ __launch_bounds__(256) void sparsemax_rows(u16* __restrict__ Sp) {
  const int wave = threadIdx.x >> 6, lane = threadIdx.x & 63;
  const int wid  = blockIdx.x * 4 + wave;
  const f16x8 zero8 = {(f16)0, (f16)0, (f16)0, (f16)0, (f16)0, (f16)0, (f16)0, (f16)0};

#pragma unroll 1
  for (int rr = 0; rr < 2; ++rr) {
    const size_t row = (size_t)wid * 2 + rr;
    f16* Srow = (f16*)Sp + row * 4096;
    f16x8 z[8];
#pragma unroll
    for (int t = 0; t < 8; ++t)
      z[t] = *(const f16x8*)(Srow + t * 512 + lane * 8);

    float tau = solve_tau(z);

    f16 tq = (f16)tau;
    f16x8 t8 = {tq, tq, tq, tq, tq, tq, tq, tq};
#pragma unroll
    for (int t = 0; t < 8; ++t)
      *(f16x8*)(Srow + t * 512 + lane * 8) =
          __builtin_elementwise_max(z[t] - t8, zero8);
  }
}

// ------------------------------------------------- fused attention (R7) -----
// Key-half staging (65.8 KB LDS -> 2 blocks/CU = 32 waves, wave cap).
// At its measured latency floor (~303 us) — frozen, do not micro-tune.
__global__ __launch_bounds__(1024, 8) void attn_sparsemax2(
    const f16* __restrict__ Q,    // [2048][1024] f16 (pre-scaled)
    const f16* __restrict__ Km,   // [4096][1024] f16
    const f16* __restrict__ Vt,   // [1024][4096] f16 (V transposed)
    u16* __restrict__ AO)         // [2048][1024] bf16
{
  constexpr int HROW = 2048 + 8;                 // f16 per row, half-keys + pad
  __shared__ __align__(16) char ldsbuf[16 * HROW * 2];   // 65,792 B
  f16*   S    = (f16*)ldsbuf;
  float* Ored = (float*)ldsbuf;                  // [kseg][dhg][256], aliased

  const int id    = blockIdx.x;
  const int head  = (id & 7) * 2 + ((id >> 3) >> 7);
  const int qblk  = (id >> 3) & 127;
  const int qbase = qblk * 16;
  const int tid   = threadIdx.x;
  const int wave  = tid >> 6, lane = tid & 63;
  const int lrow  = lane & 15, quad = lane >> 4;

  const f16* qp = Q + (size_t)(qbase + lrow) * 1024 + head * 64 + quad * 8;
  f16x8 qf0 = *(const f16x8*)qp;
  f16x8 qf1 = *(const f16x8*)(qp + 32);

  f16x8 z[8];

  // ---- QK^T in two key-halves; z row crosses the restage in registers ----
#pragma unroll
  for (int H = 0; H < 2; ++H) {
    const f16* kpb = Km + (size_t)(H * 2048 + wave * 128 + lrow) * 1024
                        + head * 64 + quad * 8;
    f16x8 kf0n = *(const f16x8*)kpb;
    f16x8 kf1n = *(const f16x8*)(kpb + 32);
#pragma unroll
    for (int kt = 0; kt < 8; ++kt) {
      f16x8 kf0 = kf0n, kf1 = kf1n;
      if (kt < 7) {
        kpb += (size_t)16 * 1024;
        kf0n = *(const f16x8*)kpb;
        kf1n = *(const f16x8*)(kpb + 32);
      }
      f32x4 sc = {0.f, 0.f, 0.f, 0.f};
      __builtin_amdgcn_s_setprio(1);
      sc = __builtin_amdgcn_mfma_f32_16x16x32_f16(qf0, kf0, sc, 0, 0, 0);
      sc = __builtin_amdgcn_mfma_f32_16x16x32_f16(qf1, kf1, sc, 0, 0, 0);
      __builtin_amdgcn_s_setprio(0);
      int lk = wave * 128 + kt * 16;             // local (in-half) key col
#pragma unroll
      for (int r = 0; r < 4; ++r)
        S[(quad * 4 + r) * HROW + lk + lrow] = (f16)sc[r];
    }
    __syncthreads();
#pragma unroll
    for (int t = 0; t < 4; ++t)
      z[H * 4 + t] = *(const f16x8*)(&S[wave * HROW + t * 512 + lane * 8]);
    __syncthreads();   // all reads done before tile is overwritten
  }

  // ---- candidate-compact sparsemax solve ----
  float m;
  {
    f16x8 mx = z[0];
#pragma unroll
    for (int t = 1; t < 8; ++t) mx = __builtin_elementwise_max(mx, z[t]);
    m = dpp_rmax(hmax8(mx));
  }
  float tau;
  f16* cbuf = &S[wave * HROW];            // own strip: exclusive until P-write
  f16  thr_h = (f16)(m - 1.01f);          // margin so RNE stays <= m-1
  bool compact_ok = ((float)thr_h <= m - 1.0f);
  int cnt = 0;
  if (compact_ok) {
#pragma unroll
    for (int t = 0; t < 8; ++t) {
#pragma unroll
      for (int j = 0; j < 8; ++j) {
        bool c = (z[t][j] > thr_h);
        unsigned long long mk = __ballot(c);
        if (mk) {                          // wave-uniform skip (most elems)
          if (c) {
            int slot = cnt + __builtin_amdgcn_mbcnt_hi(
                (unsigned)(mk >> 32),
                __builtin_amdgcn_mbcnt_lo((unsigned)mk, 0));
            if (slot < 64) cbuf[slot] = z[t][j];
          }
          cnt += (int)__popcll(mk);
        }
      }
    }
  }
  if (compact_ok && cnt <= 64) {
    asm volatile("s_waitcnt lgkmcnt(0)" ::: "memory");
    f16 craw = cbuf[lane];
    const f16 nbig = (f16)-65504.0f;
    f16 cand = (lane < cnt) ? craw : nbig;
    tau = m - 1.0f;
#pragma unroll 1
    for (int it = 0; it < 8; ++it) {
      // f16 elementwise math matches the full-row path exactly
      f16 tq = (f16)tau;
      f16 dh = cand - tq;
      f16 rh = (dh > (f16)0) ? dh : (f16)0;
      f16 ih = rh * (f16)65504.0f;
      ih = (ih < (f16)1) ? ih : (f16)1;
      float ls = dpp_rsum((float)rh);
      float lc = dpp_rsum((float)ih);
      if (lc < 0.5f) break;
      float nt = tau + (ls - 1.0f) / lc;
      if (nt == tau) break;
      tau = nt;
    }
  } else {
    tau = solve_tau(z);                    // full-row fallback (rare)
  }

  const f16 tq = (f16)tau;
  const f16x8 t8 = {tq, tq, tq, tq, tq, tq, tq, tq};
  const f16x8 zero8 = {(f16)0, (f16)0, (f16)0, (f16)0, (f16)0, (f16)0, (f16)0, (f16)0};

  const int dhg = wave & 3, kseg = wave >> 2;    // 4 dh-groups x 4 k-segments
  f32x4 oacc0 = {0.f, 0.f, 0.f, 0.f};
  f32x4 oacc1 = {0.f, 0.f, 0.f, 0.f};
  const f16* vbase = Vt + (size_t)(head * 64 + dhg * 16 + lrow) * 4096
                        + kseg * 512 + quad * 8;
  const f16* prow  = &S[lrow * HROW + kseg * 512 + quad * 8];

  // ---- P write + PV, per key-half (accumulators carry across halves) ----
#pragma unroll
  for (int H = 0; H < 2; ++H) {
    const f16* vrow = vbase + H * 2048;
    f16x8 vf0n = *(const f16x8*)(vrow);
    f16x8 vf1n = *(const f16x8*)(vrow + 32);
#pragma unroll
    for (int t = 0; t < 4; ++t)
      *(f16x8*)(&S[wave * HROW + t * 512 + lane * 8]) =
          __builtin_elementwise_max(z[H * 4 + t] - t8, zero8);
    __syncthreads();
#pragma unroll
    for (int kt = 0; kt < 16; kt += 2) {
      f16x8 vf0 = vf0n, vf1 = vf1n;
      if (kt < 14) {
        vf0n = *(const f16x8*)(vrow + (kt + 2) * 32);
        vf1n = *(const f16x8*)(vrow + (kt + 2) * 32 + 32);
      }
      f16x8 pf0 = *(const f16x8*)(prow + kt * 32);
      f16x8 pf1 = *(const f16x8*)(prow + kt * 32 + 32);
      __builtin_amdgcn_s_setprio(1);
      oacc0 = __builtin_amdgcn_mfma_f32_16x16x32_f16(pf0, vf0, oacc0, 0, 0, 0);
      oacc1 = __builtin_amdgcn_mfma_f32_16x16x32_f16(pf1, vf1, oacc1, 0, 0, 0);
      __builtin_amdgcn_s_setprio(0);
    }
    __syncthreads();   // all P reads done (H=1: before Ored aliases S)
  }
  f32x4 oacc = oacc0 + oacc1;

  // ---- cross-kseg reduction via aliased Ored, then AO store ----
  float* orp = &Ored[(kseg * 4 + dhg) * 256];
#pragma unroll
  for (int r = 0; r < 4; ++r) orp[(quad * 4 + r) * 16 + lrow] = oacc[r];
  __syncthreads();
  if (kseg == 0) {
#pragma unroll
    for (int r = 0; r < 4; ++r) {
      int idx = (quad * 4 + r) * 16 + lrow;
      float v = oacc[r] + Ored[(1 * 4 + dhg) * 256 + idx]
                        + Ored[(2 * 4 + dhg) * 256 + idx]
                        + Ored[(3 * 4 + dhg) * 256 + idx];
      AO[(size_t)(qbase + quad * 4 + r) * 1024 + head * 64 + dhg * 16 + lrow] = (u16)f2bf(v);
    }
  }
}

// ---------------------------------------------------------------- launcher --
extern "C" void kernel_launch(void* const* d_in, const int* in_sizes, int n_in,
                              void* d_out, int out_size, void* d_ws, size_t ws_size,
                              hipStream_t stream) {
  const float* enc = (const float*)d_in[0];
  const float* mem = (const float*)d_in[1];
  const float* Wq  = (const float*)d_in[2];
  const float* bq  = (const float*)d_in[3];
  const float* Wk  = (const float*)d_in[4];
  const float* bk  = (const float*)d_in[5];
  const float* Wv  = (const float*)d_in[6];
  const float* bv  = (const float*)d_in[7];
  const float* Wo  = (const float*)d_in[8];
  const float* bo  = (const float*)d_in[9];
  const float* W1  = (const float*)d_in[10];
  const float* b1  = (const float*)d_in[11];
  const float* W2  = (const float*)d_in[12];
  const float* b2  = (const float*)d_in[13];

  char* ws = (char*)d_ws;
  const size_t MB = 1024 * 1024;
  u16* enc_bf = (u16*)(ws + 0 * MB);   // 2048x1024 bf16
  u16* mem_bf = (u16*)(ws + 4 * MB);   // 4096x1024 bf16
  u16* Wq_bf  = (u16*)(ws + 12 * MB);
  u16* Wk_bf  = (u16*)(ws + 14 * MB);
  u16* Wv_bf  = (u16*)(ws + 16 * MB);
  u16* Wo_bf  = (u16*)(ws + 18 * MB);
  u16* W1_bf  = (u16*)(ws + 20 * MB);  // 4096x2048
  u16* W2_bf  = (u16*)(ws + 36 * MB);  // 1024x4096 (padded from 1000)
  u16* Qb     = (u16*)(ws + 46 * MB);  // 2048x1024 f16 (pre-scaled by 1/32)
  u16* Kb     = (u16*)(ws + 50 * MB);  // 4096x1024 f16
  u16* Vtb    = (u16*)(ws + 58 * MB);  // 1024x4096 f16 (V^T)
  u16* AO     = (u16*)(ws + 66 * MB);  // 2048x1024 bf16
  u16* OUT    = (u16*)(ws + 70 * MB);  // 2048x1024 bf16
  u16* Hh     = (u16*)(ws + 74 * MB);  // 2048x4096 bf16
  u16* Sbuf   = (u16*)(ws + 96 * MB);  // 16x2048x4096 f16 = 256 MB (split path)

  const bool split = ws_size >= (size_t)360 * MB;  // constant per harness

  ConvArgs ca;
  const float* srcs[8] = {enc, mem, Wq, Wk, Wv, Wo, W1, W2};
  u16* dsts[8] = {enc_bf, mem_bf, Wq_bf, Wk_bf, Wv_bf, Wo_bf, W1_bf, W2_bf};
  int sizes[8] = {2048 * 1024, 4096 * 1024, 1024 * 1024, 1024 * 1024,
                  1024 * 1024, 1024 * 1024, 4096 * 2048, 1000 * 4096};
  int start = 0;
  for (int i = 0; i < 8; ++i) {
    ca.src[i] = srcs[i]; ca.dst[i] = dsts[i];
    ca.start4[i] = start; start += sizes[i] / 4;
  }
  ca.start4[8] = start;
  ca.zdst = W2_bf + 1000 * 4096;
  ca.zn4  = (24 * 4096) / 4;
  convert_all<<<(start + ca.zn4 + 255) / 256, 256, 0, stream>>>(ca);

  // Q, K, V^T in one 1280-block launch (keeps CUs packed, drops 2 drains)
  QkvArgs qa;
  qa.enc = enc_bf; qa.mem = mem_bf;
  qa.Wq = Wq_bf; qa.Wk = Wk_bf; qa.Wv = Wv_bf;
  qa.bq = bq; qa.bk = bk; qa.bv = bv;
  qa.Qb = Qb; qa.Kb = Kb; qa.Vtb = Vtb;
  qkv_gemm<<<1280, 256, 0, stream>>>(qa);

  if (split) {
    gemm_nt<0, false, 2, false, 128, 1><<<dim3(32, 16, 16), 256, 0, stream>>>(
        Qb, 1024, Kb, 1024, nullptr, 0, nullptr, 0, 64, 0, nullptr,
        Sbuf, 4096, 4096, 1.0f, 64, 64, (size_t)2048 * 4096);
    sparsemax_rows<<<4096, 256, 0, stream>>>(Sbuf);
    gemm_nt<0, false, 1, false, 64, 1><<<dim3(1, 32, 16), 256, 0, stream>>>(
        Sbuf, 4096, Vtb, 4096, nullptr, 0, nullptr, 0, 4096, 0, nullptr,
        AO, 1024, 64, 1.0f, (size_t)2048 * 4096, (size_t)64 * 4096, 64);
  } else {
    attn_sparsemax2<<<2048, 1024, 0, stream>>>(
        (const f16*)Qb, (const f16*)Kb, (const f16*)Vtb, AO);
  }

  // OUT = AO @ Wo^T + bo (bf16 out)  [TM=64,TN=64: 512 blocks = 2 blocks/CU]
  gemm_nt<1, false, 1, false, 64, 0, 64><<<dim3(16, 32), 256, 0, stream>>>(
      AO, 1024, Wo_bf, 1024, nullptr, 0, nullptr, 0, 1024, 0, bo,
      OUT, 1024, 1024, 1.0f, 0, 0, 0);
  // H = relu(enc@W1a^T + OUT@W1b^T + b1)  [TM=128: 512 blocks]
  gemm_nt<1, true, 1, true, 128, 0><<<dim3(32, 16), 256, 0, stream>>>(
      enc_bf, 1024, W1_bf, 2048, OUT, 1024, W1_bf + 1024, 2048, 1024, 1024, b1,
      Hh, 4096, 4096, 1.0f, 0, 0, 0);
  // out = H @ W2^T + b2 (fp32 out, N=1000)  [TM=64,TN=64: 512 blocks]
  gemm_nt<1, false, 0, false, 64, 0, 64><<<dim3(16, 32), 256, 0, stream>>>(
      Hh, 4096, W2_bf, 4096, nullptr, 0, nullptr, 0, 4096, 0, b2,
      d_out, 1000, 1000, 1.0f, 0, 0, 0);
}